// Round 1
// baseline (71.220 us; speedup 1.0000x reference)
//
#include <hip/hip_runtime.h>

// Problem constants (from reference setup_inputs):
//   pred_emb:   (N=2, C=80, H=512, W=512) float32
//   gt_objmask: (N=2, K=32, H=512, W=512) bool (1 byte/elem)
//   gt_classes: (N=2, K=32) int32
#define N_IMG 2
#define K_OBJ 32
#define C_CH  80
#define HW    (512 * 512)
#define NK    (N_IMG * K_OBJ)

#define BLOCKS_PER_NK 16
#define BLOCK_THREADS 256

// ws layout (floats): [0,NK) cnt, [NK,2NK) s, [2NK,3NK) s2
__global__ void zero_ws(float* ws) {
    int i = threadIdx.x;
    if (i < 3 * NK) ws[i] = 0.0f;
}

__device__ __forceinline__ float wave_reduce(float v) {
    #pragma unroll
    for (int off = 32; off > 0; off >>= 1) v += __shfl_down(v, off);
    return v;
}

__global__ __launch_bounds__(BLOCK_THREADS) void partial_kernel(
    const float* __restrict__ pred,
    const unsigned char* __restrict__ mask,
    const int* __restrict__ classes,
    float* __restrict__ ws)
{
    const int nk  = blockIdx.x / BLOCKS_PER_NK;
    const int blk = blockIdx.x % BLOCKS_PER_NK;
    const int n = nk / K_OBJ;
    const int c = classes[nk];

    const float4* __restrict__ embv =
        (const float4*)(pred + (size_t)(n * C_CH + c) * HW);
    const uchar4* __restrict__ maskv =
        (const uchar4*)(mask + (size_t)nk * HW);

    const int nvec = HW / 4;  // 65536 float4/uchar4 elements
    float cnt = 0.0f, s = 0.0f, s2 = 0.0f;

    for (int i = blk * BLOCK_THREADS + threadIdx.x; i < nvec;
         i += BLOCKS_PER_NK * BLOCK_THREADS) {
        float4 e = embv[i];
        uchar4 m = maskv[i];
        if (m.x) { cnt += 1.0f; s += e.x; s2 += e.x * e.x; }
        if (m.y) { cnt += 1.0f; s += e.y; s2 += e.y * e.y; }
        if (m.z) { cnt += 1.0f; s += e.z; s2 += e.z * e.z; }
        if (m.w) { cnt += 1.0f; s += e.w; s2 += e.w * e.w; }
    }

    // 64-lane wave reduce, then cross-wave via LDS (4 waves)
    cnt = wave_reduce(cnt);
    s   = wave_reduce(s);
    s2  = wave_reduce(s2);

    __shared__ float sm[3][4];
    const int lane = threadIdx.x & 63;
    const int wave = threadIdx.x >> 6;
    if (lane == 0) { sm[0][wave] = cnt; sm[1][wave] = s; sm[2][wave] = s2; }
    __syncthreads();
    if (threadIdx.x == 0) {
        float tc = sm[0][0] + sm[0][1] + sm[0][2] + sm[0][3];
        float ts = sm[1][0] + sm[1][1] + sm[1][2] + sm[1][3];
        float t2 = sm[2][0] + sm[2][1] + sm[2][2] + sm[2][3];
        atomicAdd(&ws[nk], tc);
        atomicAdd(&ws[NK + nk], ts);
        atomicAdd(&ws[2 * NK + nk], t2);
    }
}

__global__ void finalize(const float* __restrict__ ws,
                         const int* __restrict__ classes,
                         float* __restrict__ out)
{
    __shared__ float mean[NK];
    __shared__ float var[NK];
    __shared__ float per_image[N_IMG];

    const int t = threadIdx.x;  // 64 threads, one per (n,k)
    if (t < NK) {
        float cnt = ws[t], s = ws[NK + t], s2 = ws[2 * NK + t];
        bool valid = cnt > 0.0f;
        float safe = valid ? cnt : 1.0f;
        float m = valid ? s / safe : 0.0f;
        float v = valid ? s2 / safe - m * m : 0.0f;
        mean[t] = m;
        var[t] = v;
    }
    __syncthreads();

    if (t < N_IMG) {
        const int n = t;
        float reg = 0.0f, intra = 0.0f, inter = 0.0f;
        for (int k = 0; k < K_OBJ; ++k) {
            float m = mean[n * K_OBJ + k];
            reg += m * m;
            intra += var[n * K_OBJ + k];
        }
        reg /= (float)K_OBJ;
        intra /= (float)K_OBJ;
        for (int j = 0; j < K_OBJ; ++j) {
            int cj = classes[n * K_OBJ + j];
            float mj = mean[n * K_OBJ + j];
            for (int k = j + 1; k < K_OBJ; ++k) {
                if (classes[n * K_OBJ + k] == cj) {
                    float d = mj - mean[n * K_OBJ + k];
                    float val = 1.0f - d * d;
                    inter += (val > 0.0f) ? val : 0.0f;
                }
            }
        }
        per_image[n] = inter + reg + intra;
    }
    __syncthreads();

    if (t == 0) {
        float acc = 0.0f;
        for (int n = 0; n < N_IMG; ++n) acc += per_image[n];
        out[0] = acc / (float)N_IMG * 0.1f;
    }
}

extern "C" void kernel_launch(void* const* d_in, const int* in_sizes, int n_in,
                              void* d_out, int out_size, void* d_ws, size_t ws_size,
                              hipStream_t stream) {
    const float* pred = (const float*)d_in[0];
    const unsigned char* mask = (const unsigned char*)d_in[1];
    const int* classes = (const int*)d_in[2];
    float* out = (float*)d_out;
    float* ws = (float*)d_ws;

    zero_ws<<<1, 256, 0, stream>>>(ws);
    partial_kernel<<<NK * BLOCKS_PER_NK, BLOCK_THREADS, 0, stream>>>(
        pred, mask, classes, ws);
    finalize<<<1, 64, 0, stream>>>(ws, classes, out);
}

// Round 2
// 22.225 us; speedup vs baseline: 3.2045x; 3.2045x over previous
//
#include <hip/hip_runtime.h>

// Problem constants (from reference setup_inputs):
//   pred_emb:   (N=2, C=80, H=512, W=512) float32
//   gt_objmask: (N=2, K=32, H=512, W=512) bool (1 byte/elem)
//   gt_classes: (N=2, K=32) int32
#define N_IMG 2
#define K_OBJ 32
#define C_CH  80
#define HW    (512 * 512)
#define NK    (N_IMG * K_OBJ)

#define BPN 32                    // blocks per (n,k)
#define BT  256                   // threads per block
#define SPAN (BPN * BT)           // 8192 thread-slots per (n,k)
#define NV16 (HW / 16)            // 16384 16-elem groups per (n,k)
#define ITERS (NV16 / SPAN)       // = 2, compile-time

// ws layout: ws[blk][comp][nk], comp in {cnt,s,s2}; 32*3*64 floats = 24 KB.
// Every slot is written every call by partial_kernel, so no zeroing needed.

__global__ __launch_bounds__(BT) void partial_kernel(
    const float* __restrict__ pred,
    const unsigned char* __restrict__ mask,
    const int* __restrict__ classes,
    float* __restrict__ ws)
{
    const int nk  = blockIdx.x / BPN;
    const int blk = blockIdx.x % BPN;
    const int n   = nk / K_OBJ;
    const int c   = classes[nk];

    const float4* __restrict__ embv =
        (const float4*)(pred + (size_t)(n * C_CH + c) * HW);
    const uint4* __restrict__ mv =
        (const uint4*)(mask + (size_t)nk * HW);

    unsigned int cnt_i = 0;
    float s = 0.0f, s2 = 0.0f;

    const int base = blk * BT + threadIdx.x;

#define ACCB(w, b, e) do {                                   \
        float v_ = (((w) >> (8*(b))) & 1u) ? (e) : 0.0f;     \
        s += v_; s2 = fmaf(v_, (e), s2);                     \
    } while (0)

    #pragma unroll
    for (int it = 0; it < ITERS; ++it) {
        const int i = base + it * SPAN;
        // lane covers 64 contiguous bytes of emb (4 float4) + 16 mask bytes
        const uint4  m  = mv[i];
        const float4 e0 = embv[4*i + 0];
        const float4 e1 = embv[4*i + 1];
        const float4 e2 = embv[4*i + 2];
        const float4 e3 = embv[4*i + 3];

        unsigned int t = m.x + m.y + m.z + m.w;   // per-byte sums <= 4
        cnt_i += (t * 0x01010101u) >> 24;         // sum of 16 mask bytes

        ACCB(m.x,0,e0.x); ACCB(m.x,1,e0.y); ACCB(m.x,2,e0.z); ACCB(m.x,3,e0.w);
        ACCB(m.y,0,e1.x); ACCB(m.y,1,e1.y); ACCB(m.y,2,e1.z); ACCB(m.y,3,e1.w);
        ACCB(m.z,0,e2.x); ACCB(m.z,1,e2.y); ACCB(m.z,2,e2.z); ACCB(m.z,3,e2.w);
        ACCB(m.w,0,e3.x); ACCB(m.w,1,e3.y); ACCB(m.w,2,e3.z); ACCB(m.w,3,e3.w);
    }
#undef ACCB

    float cnt = (float)cnt_i;
    #pragma unroll
    for (int off = 32; off > 0; off >>= 1) {
        cnt += __shfl_down(cnt, off);
        s   += __shfl_down(s,   off);
        s2  += __shfl_down(s2,  off);
    }

    __shared__ float sm[3][BT / 64];
    const int lane = threadIdx.x & 63;
    const int wv   = threadIdx.x >> 6;
    if (lane == 0) { sm[0][wv] = cnt; sm[1][wv] = s; sm[2][wv] = s2; }
    __syncthreads();
    if (threadIdx.x == 0) {
        float tc = 0.f, ts = 0.f, t2 = 0.f;
        #pragma unroll
        for (int w = 0; w < BT / 64; ++w) {
            tc += sm[0][w]; ts += sm[1][w]; t2 += sm[2][w];
        }
        float* dst = ws + (size_t)blk * 3 * NK;
        dst[0 * NK + nk] = tc;
        dst[1 * NK + nk] = ts;
        dst[2 * NK + nk] = t2;
    }
}

// One wave (64 threads), one thread per (n,k).
__global__ void finalize(const float* __restrict__ ws,
                         const int* __restrict__ classes,
                         float* __restrict__ out)
{
    const int t = threadIdx.x;          // 0..63
    float cnt = 0.f, s = 0.f, s2 = 0.f;
    #pragma unroll
    for (int blk = 0; blk < BPN; ++blk) {
        const float* src = ws + (size_t)blk * 3 * NK;
        cnt += src[0 * NK + t];
        s   += src[1 * NK + t];
        s2  += src[2 * NK + t];
    }
    const bool valid = cnt > 0.0f;
    const float safe = valid ? cnt : 1.0f;
    const float mean = valid ? s / safe : 0.0f;
    const float var  = valid ? s2 / safe - mean * mean : 0.0f;

    __shared__ float smean[NK];
    __shared__ int   scls[NK];
    smean[t] = mean;
    scls[t]  = classes[t];
    __syncthreads();

    const int j  = t & 31;              // instance within image
    const int nb = t & 32;              // image base (0 or 32)
    float part = (mean * mean + var) * (1.0f / K_OBJ);   // reg + intra share
    const int cj = scls[t];
    for (int k = j + 1; k < K_OBJ; ++k) {
        if (scls[nb + k] == cj) {
            float d = mean - smean[nb + k];
            float val = 1.0f - d * d;
            part += (val > 0.0f) ? val : 0.0f;
        }
    }
    // full 64-lane reduce -> I0 + I1
    #pragma unroll
    for (int off = 32; off > 0; off >>= 1) part += __shfl_down(part, off);
    if (t == 0) out[0] = part * (0.1f / N_IMG);
}

extern "C" void kernel_launch(void* const* d_in, const int* in_sizes, int n_in,
                              void* d_out, int out_size, void* d_ws, size_t ws_size,
                              hipStream_t stream) {
    const float* pred = (const float*)d_in[0];
    const unsigned char* mask = (const unsigned char*)d_in[1];
    const int* classes = (const int*)d_in[2];
    float* out = (float*)d_out;
    float* ws = (float*)d_ws;

    partial_kernel<<<NK * BPN, BT, 0, stream>>>(pred, mask, classes, ws);
    finalize<<<1, 64, 0, stream>>>(ws, classes, out);
}